// Round 1
// baseline (814.005 us; speedup 1.0000x reference)
//
#include <hip/hip_runtime.h>
#include <hip/hip_bf16.h>

// Problem constants (match reference)
#define TT 64
#define GN 1024
#define DK 128
#define NN (TT * GN)      // 65536
#define OUTC 131          // 3 + 128

// ---------------------------------------------------------------------------
// Kernel 1: per-row reciprocal norms, fp64 accumulation.
// rnorm[i] = 1.0 / max(sqrt(sum f^2), 1e-6)
// ---------------------------------------------------------------------------
__global__ void knorm(const float* __restrict__ feat, double* __restrict__ rnorm) {
    int row  = blockIdx.x * 4 + (threadIdx.x >> 6);
    int lane = threadIdx.x & 63;
    const float* fr = feat + (size_t)row * DK;
    float v0 = fr[lane];
    float v1 = fr[lane + 64];
    double s = (double)v0 * (double)v0 + (double)v1 * (double)v1;
    #pragma unroll
    for (int off = 32; off > 0; off >>= 1)
        s += __shfl_down(s, off);
    if (lane == 0) {
        double m = sqrt(s);
        if (m < 1e-6) m = 1e-6;
        rnorm[row] = 1.0 / m;
    }
}

// ---------------------------------------------------------------------------
// Kernel 2: for each t in [0,63), each g in [0,G): best[h] = argmax_h
//   dot(f[t,g], f[t+1,h]) * rnorm[t+1,h]   (fp64 accumulation; row scale
//   rnorm[t,g] dropped — argmax-invariant). Writes nxt[t*G+g] = (t+1)*G+best.
// Tiled: block = 256 threads handles 64 g-rows x all 1024 h.
// ---------------------------------------------------------------------------
#define BM 64
#define BN 64
__global__ __launch_bounds__(256) void ksim(const float* __restrict__ feat,
                                            const double* __restrict__ rnorm,
                                            int* __restrict__ nxt) {
    __shared__ float  As[DK][BM + 4];
    __shared__ float  Bs[DK][BN + 4];
    __shared__ double cval[BM][16];
    __shared__ int    cidx[BM][16];

    int t  = blockIdx.y;   // 0..62
    int gt = blockIdx.x;   // 0..15
    const float*  A  = feat  + ((size_t)t * GN + (size_t)gt * BM) * DK;
    const float*  B  = feat  + (size_t)(t + 1) * GN * DK;
    const double* rB = rnorm + (size_t)(t + 1) * GN;
    int tid = threadIdx.x;

    // Stage A (64 rows x 128 k), transposed into As[k][m], float4 global reads.
    #pragma unroll
    for (int i = 0; i < (BM * DK) / (256 * 4); ++i) {
        int idx = (i * 256 + tid) * 4;
        int m = idx >> 7;
        int k = idx & 127;
        float4 v = *(const float4*)(A + idx);
        As[k + 0][m] = v.x; As[k + 1][m] = v.y;
        As[k + 2][m] = v.z; As[k + 3][m] = v.w;
    }

    int tx = tid & 15;     // n-dim
    int ty = tid >> 4;     // m-dim
    double bv[4] = {-1e300, -1e300, -1e300, -1e300};
    int    bh[4] = {0, 0, 0, 0};

    for (int hc = 0; hc < GN / BN; ++hc) {
        __syncthreads();   // protect Bs (and As on first iter)
        #pragma unroll
        for (int i = 0; i < (BN * DK) / (256 * 4); ++i) {
            int idx = (i * 256 + tid) * 4;
            int n = idx >> 7;
            int k = idx & 127;
            float4 v = *(const float4*)(B + hc * BN * DK + idx);
            Bs[k + 0][n] = v.x; Bs[k + 1][n] = v.y;
            Bs[k + 2][n] = v.z; Bs[k + 3][n] = v.w;
        }
        __syncthreads();

        double acc[4][4];
        #pragma unroll
        for (int a = 0; a < 4; ++a)
            #pragma unroll
            for (int b = 0; b < 4; ++b) acc[a][b] = 0.0;

        #pragma unroll 4
        for (int k = 0; k < DK; ++k) {
            float4 av = *(const float4*)&As[k][ty * 4];
            float4 bw = *(const float4*)&Bs[k][tx * 4];
            double ad[4] = {av.x, av.y, av.z, av.w};
            double bd[4] = {bw.x, bw.y, bw.z, bw.w};
            #pragma unroll
            for (int a = 0; a < 4; ++a)
                #pragma unroll
                for (int b = 0; b < 4; ++b)
                    acc[a][b] = fma(ad[a], bd[b], acc[a][b]);
        }

        int hbase = hc * BN + tx * 4;
        double r0 = rB[hbase + 0], r1 = rB[hbase + 1];
        double r2 = rB[hbase + 2], r3 = rB[hbase + 3];
        #pragma unroll
        for (int a = 0; a < 4; ++a) {
            double v0 = acc[a][0] * r0, v1 = acc[a][1] * r1;
            double v2 = acc[a][2] * r2, v3 = acc[a][3] * r3;
            // ascending h, strict > keeps earliest on ties (matches jnp.argmax)
            if (v0 > bv[a]) { bv[a] = v0; bh[a] = hbase + 0; }
            if (v1 > bv[a]) { bv[a] = v1; bh[a] = hbase + 1; }
            if (v2 > bv[a]) { bv[a] = v2; bh[a] = hbase + 2; }
            if (v3 > bv[a]) { bv[a] = v3; bh[a] = hbase + 3; }
        }
    }

    // Cross-thread (over tx) reduction per row via LDS; tie -> smaller h.
    #pragma unroll
    for (int a = 0; a < 4; ++a) {
        cval[ty * 4 + a][tx] = bv[a];
        cidx[ty * 4 + a][tx] = bh[a];
    }
    __syncthreads();
    if (tid < BM) {
        double best = -1e300; int besth = 0x7FFFFFFF;
        for (int x = 0; x < 16; ++x) {
            double v = cval[tid][x];
            int    h = cidx[tid][x];
            if (v > best || (v == best && h < besth)) { best = v; besth = h; }
        }
        nxt[t * GN + gt * BM + tid] = (t + 1) * GN + besth;
    }
}

// ---------------------------------------------------------------------------
// Kernel 3: chain propagation. Single block, 1024 threads, 63 steps.
// chain_of[i] = start index (== priority) of the chain owning node i.
// Node j in group t+1 is owned by the min-priority chain among predecessors
// {i in group t : nxt[i] == j}; if none, j starts a new chain (priority j).
// ---------------------------------------------------------------------------
__global__ void kchain(const int* __restrict__ nxt, int* __restrict__ chain_of) {
    __shared__ int winner[GN];
    int tid = threadIdx.x;          // 0..1023
    chain_of[tid] = tid;            // group 0: every node starts a chain
    __syncthreads();
    for (int t = 0; t < TT - 1; ++t) {
        winner[tid] = 0x7FFFFFFF;
        __syncthreads();
        int i   = t * GN + tid;
        int j   = nxt[i];                       // global index in group t+1
        int pri = chain_of[i];
        atomicMin(&winner[j - (t + 1) * GN], pri);
        __syncthreads();
        int jg = (t + 1) * GN + tid;
        int w  = winner[tid];
        chain_of[jg] = (w == 0x7FFFFFFF) ? jg : w;
        __syncthreads();
    }
}

// ---------------------------------------------------------------------------
// Kernel 4: chain lengths via per-start atomicAdd. clen must be pre-zeroed.
// ---------------------------------------------------------------------------
__global__ void kclen(const int* __restrict__ chain_of, int* __restrict__ clen) {
    int i = blockIdx.x * 256 + threadIdx.x;
    atomicAdd(&clen[chain_of[i]], 1);
}

// ---------------------------------------------------------------------------
// Kernel 5: exclusive prefix sum over kept chain lengths (by start index).
// offset[s] = sum of clen[s'] for kept starts s' < s. Single block, 1024 thr.
// ---------------------------------------------------------------------------
__global__ void kscan(const int* __restrict__ chain_of, const int* __restrict__ clen,
                      const int* __restrict__ minp, int* __restrict__ offset) {
    __shared__ int psum[1024];
    int tid = threadIdx.x;
    int ml  = *minp;
    int base = tid * 64;
    int local = 0;
    for (int e = 0; e < 64; ++e) {
        int s  = base + e;
        int cl = clen[s];
        local += (chain_of[s] == s && cl >= ml) ? cl : 0;
    }
    psum[tid] = local;
    __syncthreads();
    for (int off = 1; off < 1024; off <<= 1) {
        int add = (tid >= off) ? psum[tid - off] : 0;
        __syncthreads();
        psum[tid] += add;
        __syncthreads();
    }
    int run = tid ? psum[tid - 1] : 0;
    for (int e = 0; e < 64; ++e) {
        int s  = base + e;
        int cl = clen[s];
        int v  = (chain_of[s] == s && cl >= ml) ? cl : 0;
        offset[s] = run;
        run += v;
    }
}

// ---------------------------------------------------------------------------
// Kernel 6: scatter rows of kept chains to packed output slots.
// slot(i) = offset[start] + (group(i) - group(start)); out pre-zeroed.
// ---------------------------------------------------------------------------
__global__ void kscatter(const float* __restrict__ coor, const float* __restrict__ feat,
                         const int* __restrict__ chain_of, const int* __restrict__ clen,
                         const int* __restrict__ offset, const int* __restrict__ minp,
                         float* __restrict__ out) {
    int i    = blockIdx.x;          // node
    int lane = threadIdx.x;         // 0..127
    int s    = chain_of[i];
    if (clen[s] < *minp) return;
    int pos  = (i >> 10) - (s >> 10);
    int row  = offset[s] + pos;
    float* orow = out + (size_t)row * OUTC;
    if (lane < 3) orow[lane] = coor[(size_t)i * 3 + lane];
    orow[3 + lane] = feat[(size_t)i * DK + lane];
}

// ---------------------------------------------------------------------------
extern "C" void kernel_launch(void* const* d_in, const int* in_sizes, int n_in,
                              void* d_out, int out_size, void* d_ws, size_t ws_size,
                              hipStream_t stream) {
    const float* coor   = (const float*)d_in[0];   // [N,3]
    const float* feat   = (const float*)d_in[1];   // [N,128]
    const int*   minlen = (const int*)d_in[2];     // scalar
    float*       out    = (float*)d_out;           // [N,131] fp32

    char* ws = (char*)d_ws;
    double* rnorm    = (double*)(ws);                       // N doubles (512 KB)
    int*    nxt      = (int*)(ws + (size_t)NN * 8);         // N ints
    int*    chain_of = (int*)(ws + (size_t)NN * 8 + (size_t)NN * 4);
    int*    clen     = (int*)(ws + (size_t)NN * 8 + (size_t)NN * 8);
    int*    offset   = (int*)(ws + (size_t)NN * 8 + (size_t)NN * 12);

    hipMemsetAsync(clen, 0, (size_t)NN * 4, stream);
    hipMemsetAsync(d_out, 0, (size_t)out_size * sizeof(float), stream);

    knorm<<<NN / 4, 256, 0, stream>>>(feat, rnorm);

    dim3 gsim(GN / BM, TT - 1);           // (16, 63)
    ksim<<<gsim, 256, 0, stream>>>(feat, rnorm, nxt);

    kchain<<<1, GN, 0, stream>>>(nxt, chain_of);
    kclen<<<NN / 256, 256, 0, stream>>>(chain_of, clen);
    kscan<<<1, 1024, 0, stream>>>(chain_of, clen, minlen, offset);
    kscatter<<<NN, DK, 0, stream>>>(coor, feat, chain_of, clen, offset, minlen, out);
}

// Round 2
// 777.965 us; speedup vs baseline: 1.0463x; 1.0463x over previous
//
#include <hip/hip_runtime.h>
#include <hip/hip_bf16.h>

// Problem constants (match reference)
#define TT 64
#define GN 1024
#define DK 128
#define NN (TT * GN)      // 65536
#define OUTC 131          // 3 + 128
#define BM 128
#define BN 128

// ---------------------------------------------------------------------------
// Kernel 1: per-row reciprocal norms, fp64 accumulation; writes both
// float (main fp32 argmax path) and double (fp64 rescue path) versions.
// ---------------------------------------------------------------------------
__global__ void knorm(const float* __restrict__ feat,
                      float* __restrict__ rnf, double* __restrict__ rnd) {
    int row  = blockIdx.x * 4 + (threadIdx.x >> 6);
    int lane = threadIdx.x & 63;
    const float* fr = feat + (size_t)row * DK;
    float v0 = fr[lane];
    float v1 = fr[lane + 64];
    double s = (double)v0 * (double)v0 + (double)v1 * (double)v1;
    #pragma unroll
    for (int off = 32; off > 0; off >>= 1)
        s += __shfl_down(s, off);
    if (lane == 0) {
        double m = sqrt(s);
        if (m < 1e-6) m = 1e-6;
        double r = 1.0 / m;
        rnd[row] = r;
        rnf[row] = (float)r;
    }
}

// LDS bank swizzle: element (row, k) lives at row*DK + (k ^ (((row>>3)&7)<<2)).
// For fragment reads (8 consecutive rows per thread, row>>3 uniform), the
// 16 distinct lane addresses spread over all 8 bank-groups -> 2-way = free.
__device__ __forceinline__ int swz(int row, int k) {
    return k ^ (((row >> 3) & 7) << 2);
}

// ---------------------------------------------------------------------------
// Kernel 2: best-cosine-match graph. Per block: A-tile = 128 rows of group t,
// argmax over all 1024 rows of group t+1. fp32 8x8 register tile per thread,
// top-2 tracking; near-ties (gap < 1e-3) recomputed in fp64 (rare).
// ---------------------------------------------------------------------------
__global__ __launch_bounds__(256) void ksim(const float* __restrict__ feat,
                                            const float* __restrict__ rnf,
                                            const double* __restrict__ rnd,
                                            int* __restrict__ nxt) {
    __shared__ float As[BM * DK];   // 64 KB
    __shared__ float Bs[BN * DK];   // 64 KB (reused for reductions at the end)

    int t   = blockIdx.y;   // 0..62
    int gt  = blockIdx.x;   // 0..7
    int tid = threadIdx.x;
    int tx  = tid & 15;     // column group
    int ty  = tid >> 4;     // row group
    const float* A = feat + (size_t)(t * GN + gt * BM) * DK;
    const float* B = feat + (size_t)(t + 1) * GN * DK;

    // Stage A tile (128x128 fp32), swizzled, float4 global loads.
    #pragma unroll
    for (int i = 0; i < 16; ++i) {
        int e = (i * 256 + tid) * 4;
        int r = e >> 7, k = e & 127;
        float4 v = *(const float4*)(A + e);
        *(float4*)&As[r * DK + swz(r, k)] = v;
    }

    float bv1[8], bv2[8]; int bh[8];
    #pragma unroll
    for (int i = 0; i < 8; ++i) { bv1[i] = -3.4e38f; bv2[i] = -3.4e38f; bh[i] = 0; }

    int arow = ty * 8;
    int brow = tx * 8;
    int sa = (ty & 7) << 2;
    int sb = (tx & 7) << 2;

    for (int hc = 0; hc < GN / BN; ++hc) {
        __syncthreads();   // protect Bs reuse
        #pragma unroll
        for (int i = 0; i < 16; ++i) {
            int e = (i * 256 + tid) * 4;
            int r = e >> 7, k = e & 127;
            float4 v = *(const float4*)(B + (size_t)hc * BN * DK + e);
            *(float4*)&Bs[r * DK + swz(r, k)] = v;
        }
        // prefetch rnorm for this thread's 8 columns (overlaps with k-loop)
        float4 rna = *(const float4*)(rnf + (t + 1) * GN + hc * BN + brow);
        float4 rnb = *(const float4*)(rnf + (t + 1) * GN + hc * BN + brow + 4);
        __syncthreads();

        float acc[8][8];
        #pragma unroll
        for (int i = 0; i < 8; ++i)
            #pragma unroll
            for (int j = 0; j < 8; ++j) acc[i][j] = 0.0f;

        #pragma unroll 4
        for (int k4 = 0; k4 < DK; k4 += 4) {
            float4 a[8], b[8];
            int ka = k4 ^ sa;
            int kb = k4 ^ sb;
            #pragma unroll
            for (int i = 0; i < 8; ++i)
                a[i] = *(const float4*)&As[(arow + i) * DK + ka];
            #pragma unroll
            for (int j = 0; j < 8; ++j)
                b[j] = *(const float4*)&Bs[(brow + j) * DK + kb];
            #pragma unroll
            for (int i = 0; i < 8; ++i)
                #pragma unroll
                for (int j = 0; j < 8; ++j) {
                    acc[i][j] = fmaf(a[i].x, b[j].x, acc[i][j]);
                    acc[i][j] = fmaf(a[i].y, b[j].y, acc[i][j]);
                    acc[i][j] = fmaf(a[i].z, b[j].z, acc[i][j]);
                    acc[i][j] = fmaf(a[i].w, b[j].w, acc[i][j]);
                }
        }

        float rn[8] = {rna.x, rna.y, rna.z, rna.w, rnb.x, rnb.y, rnb.z, rnb.w};
        #pragma unroll
        for (int j = 0; j < 8; ++j) {
            int h = hc * BN + brow + j;
            #pragma unroll
            for (int i = 0; i < 8; ++i) {
                float v = acc[i][j] * rn[j];
                if (v > bv1[i]) { bv2[i] = bv1[i]; bv1[i] = v; bh[i] = h; }
                else if (v > bv2[i]) bv2[i] = v;
            }
        }
    }

    // ---- cross-thread top-2 merge (overlay reduction arrays on Bs) ----
    __syncthreads();
    float*  rv1   = Bs;                        // [16][128]
    float*  rv2   = Bs + 2048;                 // [16][128]
    int*    ri    = (int*)(Bs + 4096);         // [16][128]
    int*    nflag = (int*)(Bs + 6144);
    int*    lst   = (int*)(Bs + 6160);         // up to 128
    double* rbv   = (double*)(Bs + 8192);      // [256]
    int*    rbi   = (int*)(Bs + 8704);         // [256]

    #pragma unroll
    for (int i = 0; i < 8; ++i) {
        rv1[tx * 128 + arow + i] = bv1[i];
        rv2[tx * 128 + arow + i] = bv2[i];
        ri [tx * 128 + arow + i] = bh[i];
    }
    if (tid == 0) *nflag = 0;
    __syncthreads();

    if (tid < BM) {
        float best = -3.4e38f, sec = -3.4e38f, bw2 = -3.4e38f;
        int   bi = 0x7fffffff;
        for (int x = 0; x < 16; ++x) {
            float v1 = rv1[x * 128 + tid];
            float v2 = rv2[x * 128 + tid];
            int  idx = ri [x * 128 + tid];
            if (v1 > best || (v1 == best && idx < bi)) {
                sec = fmaxf(sec, best);
                best = v1; bi = idx; bw2 = v2;
            } else {
                sec = fmaxf(sec, v1);
            }
        }
        sec = fmaxf(sec, bw2);
        if (best - sec < 1e-3f) {
            int p = atomicAdd(nflag, 1);
            lst[p] = tid;                       // fp64 rescue needed
        } else {
            nxt[t * GN + gt * BM + tid] = (t + 1) * GN + bi;
        }
    }
    __syncthreads();

    // ---- fp64 rescue for near-tie rows (expected ~0.3 rows per block) ----
    int nf = *nflag;
    for (int fi = 0; fi < nf; ++fi) {
        int r  = lst[fi];
        int sr = ((r >> 3) & 7) << 2;
        double bestv = -1e300; int besth = 0x7fffffff;
        for (int h = tid; h < GN; h += 256) {
            const float* Brow = B + (size_t)h * DK;
            double s = 0.0;
            for (int k4 = 0; k4 < DK; k4 += 4) {
                float4 aa = *(const float4*)&As[r * DK + (k4 ^ sr)];
                float4 bb = *(const float4*)(Brow + k4);
                s = fma((double)aa.x, (double)bb.x, s);
                s = fma((double)aa.y, (double)bb.y, s);
                s = fma((double)aa.z, (double)bb.z, s);
                s = fma((double)aa.w, (double)bb.w, s);
            }
            s *= rnd[(t + 1) * GN + h];
            if (s > bestv) { bestv = s; besth = h; }   // h ascending per thread
        }
        rbv[tid] = bestv; rbi[tid] = besth;
        __syncthreads();
        if (tid == 0) {
            double bv = -1e300; int bh2 = 0x7fffffff;
            for (int x = 0; x < 256; ++x) {
                double v = rbv[x]; int hh = rbi[x];
                if (v > bv || (v == bv && hh < bh2)) { bv = v; bh2 = hh; }
            }
            nxt[t * GN + gt * BM + r] = (t + 1) * GN + bh2;
        }
        __syncthreads();
    }
}

// ---------------------------------------------------------------------------
// Kernel 3: chain propagation + lengths + kept-offset scan, one block.
// chain_of[i] = start index (priority) of owning chain. Node j in group t+1
// is claimed by the min-priority chain among predecessors; else starts new.
// Lengths tracked incrementally (write clen exactly once, when chain dies).
// ---------------------------------------------------------------------------
__global__ void kgraph(const int* __restrict__ nxt, int* __restrict__ chain_of,
                       int* __restrict__ clen, const int* __restrict__ minp,
                       int* __restrict__ offset) {
    __shared__ int winner[GN];
    __shared__ int tlen[GN];
    __shared__ int psum[1024];
    int g = threadIdx.x;            // 0..1023
    int mychain = g, mylen = 1;     // group 0: every node starts a chain
    chain_of[g] = g;
    for (int t = 0; t < TT - 1; ++t) {
        winner[g] = 0x7fffffff;
        __syncthreads();
        int j = nxt[t * GN + g] - (t + 1) * GN;    // target slot in next group
        atomicMin(&winner[j], mychain);
        __syncthreads();
        if (winner[j] == mychain) tlen[j] = mylen + 1;   // unique winner
        else                      clen[mychain] = mylen; // chain dies here
        __syncthreads();
        int w = winner[g];
        int node = (t + 1) * GN + g;
        if (w == 0x7fffffff) { mychain = node; mylen = 1; }
        else                 { mychain = w;    mylen = tlen[g]; }
        chain_of[node] = mychain;
        __syncthreads();
    }
    clen[mychain] = mylen;          // surviving chains end at group 63
    __syncthreads();

    // exclusive prefix sum of kept chain lengths over start indices
    int ml = *minp;
    int base = g * 64;
    int local = 0;
    for (int e = 0; e < 64; ++e) {
        int s = base + e;
        if (chain_of[s] == s) { int cl = clen[s]; if (cl >= ml) local += cl; }
    }
    psum[g] = local;
    __syncthreads();
    for (int off = 1; off < 1024; off <<= 1) {
        int add = (g >= off) ? psum[g - off] : 0;
        __syncthreads();
        psum[g] += add;
        __syncthreads();
    }
    int run = g ? psum[g - 1] : 0;
    for (int e = 0; e < 64; ++e) {
        int s = base + e;
        int v = 0;
        if (chain_of[s] == s) { int cl = clen[s]; if (cl >= ml) v = cl; }
        offset[s] = run;
        run += v;
    }
}

// ---------------------------------------------------------------------------
// Kernel 4: scatter rows of kept chains to packed output slots.
// slot(i) = offset[start] + (group(i) - group(start)); out pre-zeroed.
// ---------------------------------------------------------------------------
__global__ void kscatter(const float* __restrict__ coor, const float* __restrict__ feat,
                         const int* __restrict__ chain_of, const int* __restrict__ clen,
                         const int* __restrict__ offset, const int* __restrict__ minp,
                         float* __restrict__ out) {
    int i    = blockIdx.x;          // node
    int lane = threadIdx.x;         // 0..127
    int s    = chain_of[i];
    if (clen[s] < *minp) return;
    int pos  = (i >> 10) - (s >> 10);
    int row  = offset[s] + pos;
    float* orow = out + (size_t)row * OUTC;
    if (lane < 3) orow[lane] = coor[(size_t)i * 3 + lane];
    orow[3 + lane] = feat[(size_t)i * DK + lane];
}

// ---------------------------------------------------------------------------
extern "C" void kernel_launch(void* const* d_in, const int* in_sizes, int n_in,
                              void* d_out, int out_size, void* d_ws, size_t ws_size,
                              hipStream_t stream) {
    const float* coor   = (const float*)d_in[0];   // [N,3]
    const float* feat   = (const float*)d_in[1];   // [N,128]
    const int*   minlen = (const int*)d_in[2];     // scalar
    float*       out    = (float*)d_out;           // [N,131] fp32

    char* ws = (char*)d_ws;
    double* rnd      = (double*)(ws);                              // N doubles
    float*  rnf      = (float*)(ws + (size_t)NN * 8);              // N floats
    int*    nxt      = (int*)(ws + (size_t)NN * 8 + (size_t)NN * 4);
    int*    chain_of = (int*)(ws + (size_t)NN * 8 + (size_t)NN * 8);
    int*    clen     = (int*)(ws + (size_t)NN * 8 + (size_t)NN * 12);
    int*    offset   = (int*)(ws + (size_t)NN * 8 + (size_t)NN * 16);

    hipMemsetAsync(d_out, 0, (size_t)out_size * sizeof(float), stream);

    knorm<<<NN / 4, 256, 0, stream>>>(feat, rnf, rnd);

    dim3 gsim(GN / BM, TT - 1);           // (8, 63)
    ksim<<<gsim, 256, 0, stream>>>(feat, rnf, rnd, nxt);

    kgraph<<<1, GN, 0, stream>>>(nxt, chain_of, clen, minlen, offset);
    kscatter<<<NN, DK, 0, stream>>>(coor, feat, chain_of, clen, offset, minlen, out);
}

// Round 4
// 694.772 us; speedup vs baseline: 1.1716x; 1.1197x over previous
//
#include <hip/hip_runtime.h>
#include <hip/hip_bf16.h>
#include <hip/hip_fp16.h>

// Problem constants (match reference)
#define TT 64
#define GN 1024
#define DK 128
#define NN (TT * GN)      // 65536
#define OUTC 131          // 3 + 128
#define BM 128            // block A-rows
#define BN 128            // B chunk per hc iteration
#define SR 68             // LDS row stride in ints (136 fp16 = 272 B)
#define TAU 8e-3f         // rescue threshold, 14 sigma of fp16-induced sim error

typedef _Float16 f16x8 __attribute__((ext_vector_type(8)));
typedef float    f32x4 __attribute__((ext_vector_type(4)));

// ---------------------------------------------------------------------------
// Kernel 1: per-row reciprocal norms, fp64 accumulation; fp32 + fp64 copies.
// ---------------------------------------------------------------------------
__global__ void knorm(const float* __restrict__ feat,
                      float* __restrict__ rnf, double* __restrict__ rnd) {
    int row  = blockIdx.x * 4 + (threadIdx.x >> 6);
    int lane = threadIdx.x & 63;
    const float* fr = feat + (size_t)row * DK;
    float v0 = fr[lane];
    float v1 = fr[lane + 64];
    double s = (double)v0 * (double)v0 + (double)v1 * (double)v1;
    #pragma unroll
    for (int off = 32; off > 0; off >>= 1)
        s += __shfl_down(s, off);
    if (lane == 0) {
        double m = sqrt(s);
        if (m < 1e-6) m = 1e-6;
        double r = 1.0 / m;
        rnd[row] = r;
        rnf[row] = (float)r;
    }
}

// fp32 -> fp16 round-to-nearest-even, as raw 16 bits
__device__ __forceinline__ unsigned f2h(float f) {
    return (unsigned)__half_as_ushort(__float2half(f));
}

// Stage a 128x128 fp32 tile -> LDS fp16, row stride SR ints.
__device__ __forceinline__ void stage_tile(const float* __restrict__ src,
                                           int* __restrict__ dst, int tid) {
    #pragma unroll
    for (int i = 0; i < 8; ++i) {
        int e = (i * 256 + tid) * 8;        // 8 consecutive floats
        int r = e >> 7, k = e & 127;
        float4 v0 = *(const float4*)(src + e);
        float4 v1 = *(const float4*)(src + e + 4);
        int4 p;
        p.x = f2h(v0.x) | (f2h(v0.y) << 16);
        p.y = f2h(v0.z) | (f2h(v0.w) << 16);
        p.z = f2h(v1.x) | (f2h(v1.y) << 16);
        p.w = f2h(v1.z) | (f2h(v1.w) << 16);
        *(int4*)(dst + r * SR + (k >> 1)) = p;
    }
}

__device__ __forceinline__ f16x8 ldfrag(const int* tile, int row, int kc, int lq) {
    int4 v = *(const int4*)(tile + row * SR + (kc >> 1) + (lq << 2));
    return __builtin_bit_cast(f16x8, v);
}

// ---------------------------------------------------------------------------
// Kernel 2: best-cosine-match graph via fp16 MFMA (16x16x32), top-2 tracking,
// fp64 rescue for rows with gap < TAU (exact: matches rounds 1-2 fp64 path).
// Block: 256 thr = 4 waves; block tile 128(m) x 128(n) per hc, 8 hc chunks.
// Wave tile 64x64 = 4x4 MFMA tiles.
// ---------------------------------------------------------------------------
__global__ __launch_bounds__(256) void ksim(const float* __restrict__ feat,
                                            const float* __restrict__ rnf,
                                            const double* __restrict__ rnd,
                                            int* __restrict__ nxt) {
    __shared__ int lds[2 * BM * SR];       // 69632 B: A tile + B tile
    __shared__ int nflag;
    __shared__ int lst[BM];

    int* Atile = lds;
    int* Btile = lds + BM * SR;

    int t   = blockIdx.y;                  // 0..62
    int gt  = blockIdx.x;                  // 0..7
    int tid = threadIdx.x;
    int wave = tid >> 6;
    int lane = tid & 63;
    int la = lane & 15;                    // fragment row/col within 16-tile
    int lq = lane >> 4;                    // quad
    int wr = (wave & 1) * 64;              // wave row offset in block tile
    int wc = (wave >> 1) * 64;             // wave col offset in B chunk

    const float* A = feat + (size_t)(t * GN + gt * BM) * DK;
    const float* B = feat + (size_t)(t + 1) * GN * DK;
    const float* rB = rnf + (size_t)(t + 1) * GN;

    stage_tile(A, Atile, tid);

    // per-lane top-2 over 16 m-slots (slot s = rt*4 + reg)
    float t1[16], t2[16]; int i1[16];
    #pragma unroll
    for (int s = 0; s < 16; ++s) { t1[s] = -3.4e38f; t2[s] = -3.4e38f; i1[s] = 0x7fffffff; }

    for (int hc = 0; hc < GN / BN; ++hc) {
        __syncthreads();                   // previous tile reads done (covers A stage too)
        stage_tile(B + (size_t)hc * BN * DK, Btile, tid);
        __syncthreads();

        f32x4 acc[4][4];
        #pragma unroll
        for (int rt = 0; rt < 4; ++rt)
            #pragma unroll
            for (int ct = 0; ct < 4; ++ct)
                acc[rt][ct] = (f32x4){0.f, 0.f, 0.f, 0.f};

        #pragma unroll
        for (int kc = 0; kc < DK; kc += 32) {
            f16x8 af[4], bfr[4];
            #pragma unroll
            for (int rt = 0; rt < 4; ++rt) af[rt]  = ldfrag(Atile, wr + rt * 16 + la, kc, lq);
            #pragma unroll
            for (int ct = 0; ct < 4; ++ct) bfr[ct] = ldfrag(Btile, wc + ct * 16 + la, kc, lq);
            #pragma unroll
            for (int rt = 0; rt < 4; ++rt)
                #pragma unroll
                for (int ct = 0; ct < 4; ++ct)
                    acc[rt][ct] = __builtin_amdgcn_mfma_f32_16x16x32_f16(
                        af[rt], bfr[ct], acc[rt][ct], 0, 0, 0);
        }

        // scale by 1/|b| and update top-2 (n ascending within lane)
        #pragma unroll
        for (int ct = 0; ct < 4; ++ct) {
            int n = hc * BN + wc + ct * 16 + la;
            float rn = rB[n];
            #pragma unroll
            for (int rt = 0; rt < 4; ++rt) {
                #pragma unroll
                for (int reg = 0; reg < 4; ++reg) {
                    float v = acc[rt][ct][reg] * rn;
                    int s = rt * 4 + reg;
                    if (v > t1[s]) { t2[s] = t1[s]; t1[s] = v; i1[s] = n; }
                    else if (v > t2[s]) t2[s] = v;
                }
            }
        }
    }

    // ---- cross-lane merge: overlay padded arrays on the tile LDS ----
    __syncthreads();
    float* mg1 = (float*)lds;              // [128][33]
    float* mg2 = (float*)(lds + 4224);     // [128][33]
    int*   mgi = lds + 8448;               // [128][33]
    if (tid == 0) nflag = 0;
    int col = (wave >> 1) * 16 + la;       // 0..31
    #pragma unroll
    for (int s = 0; s < 16; ++s) {
        int m = wr + (s >> 2) * 16 + lq * 4 + (s & 3);
        mg1[m * 33 + col] = t1[s];
        mg2[m * 33 + col] = t2[s];
        mgi[m * 33 + col] = i1[s];
    }
    __syncthreads();

    if (tid < BM) {
        float best = -3.4e38f, sec = -3.4e38f, bw2 = -3.4e38f;
        int bi = 0x7fffffff;
        for (int c = 0; c < 32; ++c) {
            float v1 = mg1[tid * 33 + c];
            float v2 = mg2[tid * 33 + c];
            int  idx = mgi[tid * 33 + c];
            if (v1 > best || (v1 == best && idx < bi)) {
                sec = fmaxf(sec, best);
                best = v1; bi = idx; bw2 = v2;
            } else {
                sec = fmaxf(sec, v1);
            }
        }
        sec = fmaxf(sec, bw2);
        if (best - sec < TAU) {
            int p = atomicAdd(&nflag, 1);
            lst[p] = tid;                  // fp64 rescue
        } else {
            nxt[t * GN + gt * BM + tid] = (t + 1) * GN + bi;
        }
    }
    __syncthreads();

    // ---- fp64 rescue, wave-parallel (exact: matches rounds 1-2 fp64 path) ----
    int nf = nflag;
    for (int fi = wave; fi < nf; fi += 4) {
        int r = lst[fi];
        const float* Arow = feat + (size_t)(t * GN + gt * BM + r) * DK;
        double bv = -1e300; int bi2 = 0x7fffffff;
        for (int hh = 0; hh < 16; ++hh) {
            int h = hh * 64 + lane;
            const float* Brow = B + (size_t)h * DK;
            double s = 0.0;
            #pragma unroll 8
            for (int k = 0; k < DK; k += 4) {
                float4 a = *(const float4*)(Arow + k);
                float4 b = *(const float4*)(Brow + k);
                s = fma((double)a.x, (double)b.x, s);
                s = fma((double)a.y, (double)b.y, s);
                s = fma((double)a.z, (double)b.z, s);
                s = fma((double)a.w, (double)b.w, s);
            }
            s *= rnd[(t + 1) * GN + h];
            if (s > bv || (s == bv && h < bi2)) { bv = s; bi2 = h; }
        }
        #pragma unroll
        for (int off = 32; off > 0; off >>= 1) {
            double ov = __shfl_down(bv, off);
            int    oi = __shfl_down(bi2, off);
            if (ov > bv || (ov == bv && oi < bi2)) { bv = ov; bi2 = oi; }
        }
        if (lane == 0) nxt[t * GN + gt * BM + r] = (t + 1) * GN + bi2;
    }
}

// ---------------------------------------------------------------------------
// Kernel 3: chain propagation + lengths + kept-offset scan, one block.
// ---------------------------------------------------------------------------
__global__ void kgraph(const int* __restrict__ nxt, int* __restrict__ chain_of,
                       int* __restrict__ clen, const int* __restrict__ minp,
                       int* __restrict__ offset) {
    __shared__ int winner[GN];
    __shared__ int tlen[GN];
    __shared__ int psum[1024];
    int g = threadIdx.x;            // 0..1023
    int mychain = g, mylen = 1;     // group 0: every node starts a chain
    chain_of[g] = g;
    int nxt_cur = nxt[g];           // prefetch t=0
    for (int t = 0; t < TT - 1; ++t) {
        int j = nxt_cur - (t + 1) * GN;         // target slot in next group
        if (t + 1 < TT - 1) nxt_cur = nxt[(t + 1) * GN + g];   // prefetch
        winner[g] = 0x7fffffff;
        __syncthreads();
        atomicMin(&winner[j], mychain);
        __syncthreads();
        if (winner[j] == mychain) tlen[j] = mylen + 1;   // unique winner
        else                      clen[mychain] = mylen; // chain dies here
        __syncthreads();
        int w = winner[g];
        int node = (t + 1) * GN + g;
        if (w == 0x7fffffff) { mychain = node; mylen = 1; }
        else                 { mychain = w;    mylen = tlen[g]; }
        chain_of[node] = mychain;
        __syncthreads();
    }
    clen[mychain] = mylen;          // surviving chains end at group 63
    __syncthreads();

    // exclusive prefix sum of kept chain lengths over start indices
    int ml = *minp;
    int base = g * 64;
    int local = 0;
    for (int e = 0; e < 64; ++e) {
        int s = base + e;
        if (chain_of[s] == s) { int cl = clen[s]; if (cl >= ml) local += cl; }
    }
    psum[g] = local;
    __syncthreads();
    for (int off = 1; off < 1024; off <<= 1) {
        int add = (g >= off) ? psum[g - off] : 0;
        __syncthreads();
        psum[g] += add;
        __syncthreads();
    }
    int run = g ? psum[g - 1] : 0;
    for (int e = 0; e < 64; ++e) {
        int s = base + e;
        int v = 0;
        if (chain_of[s] == s) { int cl = clen[s]; if (cl >= ml) v = cl; }
        offset[s] = run;
        run += v;
    }
}

// ---------------------------------------------------------------------------
// Kernel 4: scatter kept rows, one wave per node (4 nodes / 256-thr block).
// ---------------------------------------------------------------------------
__global__ void kscatter(const float* __restrict__ coor, const float* __restrict__ feat,
                         const int* __restrict__ chain_of, const int* __restrict__ clen,
                         const int* __restrict__ offset, const int* __restrict__ minp,
                         float* __restrict__ out) {
    int node = blockIdx.x * 4 + (threadIdx.x >> 6);
    int lane = threadIdx.x & 63;
    int s = chain_of[node];
    if (clen[s] < *minp) return;
    int row = offset[s] + (node >> 10) - (s >> 10);
    float* orow = out + (size_t)row * OUTC;
    const float* f = feat + (size_t)node * DK;
    if (lane < 3) orow[lane] = coor[(size_t)node * 3 + lane];
    orow[3 + lane]  = f[lane];
    orow[67 + lane] = f[64 + lane];
}

// ---------------------------------------------------------------------------
extern "C" void kernel_launch(void* const* d_in, const int* in_sizes, int n_in,
                              void* d_out, int out_size, void* d_ws, size_t ws_size,
                              hipStream_t stream) {
    const float* coor   = (const float*)d_in[0];   // [N,3]
    const float* feat   = (const float*)d_in[1];   // [N,128]
    const int*   minlen = (const int*)d_in[2];     // scalar
    float*       out    = (float*)d_out;           // [N,131] fp32

    char* ws = (char*)d_ws;
    double* rnd      = (double*)(ws);                              // N doubles
    float*  rnf      = (float*)(ws + (size_t)NN * 8);              // N floats
    int*    nxt      = (int*)(ws + (size_t)NN * 8 + (size_t)NN * 4);
    int*    chain_of = (int*)(ws + (size_t)NN * 8 + (size_t)NN * 8);
    int*    clen     = (int*)(ws + (size_t)NN * 8 + (size_t)NN * 12);
    int*    offset   = (int*)(ws + (size_t)NN * 8 + (size_t)NN * 16);

    hipMemsetAsync(d_out, 0, (size_t)out_size * sizeof(float), stream);

    knorm<<<NN / 4, 256, 0, stream>>>(feat, rnf, rnd);

    dim3 gsim(GN / BM, TT - 1);           // (8, 63)
    ksim<<<gsim, 256, 0, stream>>>(feat, rnf, rnd, nxt);

    kgraph<<<1, GN, 0, stream>>>(nxt, chain_of, clen, minlen, offset);
    kscatter<<<NN / 4, 256, 0, stream>>>(coor, feat, chain_of, clen, offset, minlen, out);
}

// Round 5
// 560.075 us; speedup vs baseline: 1.4534x; 1.2405x over previous
//
#include <hip/hip_runtime.h>
#include <hip/hip_bf16.h>
#include <hip/hip_fp16.h>

// Problem constants (match reference)
#define TT 64
#define GN 1024
#define DK 128
#define NN (TT * GN)      // 65536
#define OUTC 131          // 3 + 128
#define BM 64             // block A-rows
#define BN 128            // B chunk per hc iteration
#define SR 68             // LDS row stride in ints (136 fp16 = 272 B)
#define TAU 8e-3f         // rescue threshold, 14 sigma of fp16-induced sim error

typedef _Float16 f16x8 __attribute__((ext_vector_type(8)));
typedef float    f32x4 __attribute__((ext_vector_type(4)));

// fp32 -> fp16 round-to-nearest-even, as raw 16 bits
__device__ __forceinline__ unsigned f2h(float f) {
    return (unsigned)__half_as_ushort(__float2half(f));
}

// ---------------------------------------------------------------------------
// Kernel 1: fused fp16 conversion + per-row reciprocal norms (fp64 accum).
// One wave per row: lane reads float2, packs to half2, shuffle-reduces norm.
// ---------------------------------------------------------------------------
__global__ void kconv(const float* __restrict__ feat, unsigned* __restrict__ fh,
                      float* __restrict__ rnf, double* __restrict__ rnd) {
    int row  = blockIdx.x * 4 + (threadIdx.x >> 6);
    int lane = threadIdx.x & 63;
    const float* fr = feat + (size_t)row * DK;
    float2 v = *(const float2*)(fr + lane * 2);
    fh[(size_t)row * 64 + lane] = f2h(v.x) | (f2h(v.y) << 16);
    double s = (double)v.x * (double)v.x + (double)v.y * (double)v.y;
    #pragma unroll
    for (int off = 32; off > 0; off >>= 1)
        s += __shfl_down(s, off);
    if (lane == 0) {
        double m = sqrt(s);
        if (m < 1e-6) m = 1e-6;
        double r = 1.0 / m;
        rnd[row] = r;
        rnf[row] = (float)r;
    }
}

__device__ __forceinline__ f16x8 ldfrag(const int* tile, int row, int kc, int lq) {
    int4 v = *(const int4*)(tile + row * SR + (kc >> 1) + (lq << 2));
    return __builtin_bit_cast(f16x8, v);
}

// ---------------------------------------------------------------------------
// Kernel 2: best-cosine-match graph via fp16 MFMA (16x16x32), top-2 tracking,
// fp64 rescue for rows with gap < TAU (exact fp64 path from rounds 1-2).
// Linear grid of 1024; XCD-aware mapping: all 16 blocks of a given t land on
// one XCD so B_t is fetched from HBM once, then L2-hit. BM=64 rows per block,
// 4 waves split the 128-col B chunk (wave tile 64x32 = 4x2 MFMA tiles).
// ---------------------------------------------------------------------------
__global__ __launch_bounds__(256) void ksim(const float* __restrict__ feat,
                                            const unsigned* __restrict__ fh,
                                            const float* __restrict__ rnf,
                                            const double* __restrict__ rnd,
                                            int* __restrict__ nxt) {
    __shared__ int lds[(BM + BN) * SR];    // 52224 B: A tile (64) + B tile (128)
    __shared__ int nflag;
    __shared__ int lst[BM];

    int id = blockIdx.x;
    int t  = (id & 7) + 8 * ((id >> 3) & 7);   // same t -> same XCD (id%8)
    int gt = id >> 6;                          // 0..15
    if (t >= TT - 1) return;                   // 16 idle blocks (t==63)

    int* Atile = lds;
    int* Btile = lds + BM * SR;

    int tid  = threadIdx.x;
    int wave = tid >> 6;
    int lane = tid & 63;
    int la = lane & 15;
    int lq = lane >> 4;
    int wcl = wave * 32;                   // wave col offset in B chunk

    const int* Ah = (const int*)fh + (size_t)(t * GN + gt * BM) * 64;
    const int* Bh = (const int*)fh + (size_t)(t + 1) * GN * 64;
    const float* rB = rnf + (size_t)(t + 1) * GN;

    // Stage A tile (64 rows x 128 fp16), int4 = 8 halves per thread-iter.
    #pragma unroll
    for (int i = 0; i < 4; ++i) {
        int e = (i * 256 + tid) * 8;       // half index
        int r = e >> 7, k = e & 127;
        int4 v = *(const int4*)(Ah + (e >> 1));
        *(int4*)&Atile[r * SR + (k >> 1)] = v;
    }

    // per-lane top-2 over 16 m-slots (slot s = rt*4 + reg; m = (s>>2)*16+lq*4+(s&3))
    float t1[16], t2[16]; int i1[16];
    #pragma unroll
    for (int s = 0; s < 16; ++s) { t1[s] = -3.4e38f; t2[s] = -3.4e38f; i1[s] = 0x7fffffff; }

    for (int hc = 0; hc < GN / BN; ++hc) {
        __syncthreads();                   // previous tile reads done (covers A stage)
        #pragma unroll
        for (int i = 0; i < 8; ++i) {
            int e = (i * 256 + tid) * 8;
            int r = e >> 7, k = e & 127;
            int4 v = *(const int4*)(Bh + (size_t)hc * BN * 64 + (e >> 1));
            *(int4*)&Btile[r * SR + (k >> 1)] = v;
        }
        float rn0 = rB[hc * BN + wcl + la];
        float rn1 = rB[hc * BN + wcl + 16 + la];
        __syncthreads();

        f32x4 acc[4][2];
        #pragma unroll
        for (int rt = 0; rt < 4; ++rt)
            #pragma unroll
            for (int ct = 0; ct < 2; ++ct)
                acc[rt][ct] = (f32x4){0.f, 0.f, 0.f, 0.f};

        #pragma unroll
        for (int kc = 0; kc < DK; kc += 32) {
            f16x8 af[4], bfr[2];
            #pragma unroll
            for (int rt = 0; rt < 4; ++rt) af[rt]  = ldfrag(Atile, rt * 16 + la, kc, lq);
            #pragma unroll
            for (int ct = 0; ct < 2; ++ct) bfr[ct] = ldfrag(Btile, wcl + ct * 16 + la, kc, lq);
            #pragma unroll
            for (int rt = 0; rt < 4; ++rt)
                #pragma unroll
                for (int ct = 0; ct < 2; ++ct)
                    acc[rt][ct] = __builtin_amdgcn_mfma_f32_16x16x32_f16(
                        af[rt], bfr[ct], acc[rt][ct], 0, 0, 0);
        }

        // scale by 1/|b| and update top-2 (med3 keeps exact second-best)
        #pragma unroll
        for (int ct = 0; ct < 2; ++ct) {
            int n = hc * BN + wcl + ct * 16 + la;
            float rn = ct ? rn1 : rn0;
            #pragma unroll
            for (int rt = 0; rt < 4; ++rt) {
                #pragma unroll
                for (int reg = 0; reg < 4; ++reg) {
                    float v = acc[rt][ct][reg] * rn;
                    int s = rt * 4 + reg;
                    t2[s] = fmaxf(t2[s], fminf(v, t1[s]));   // med3(v,t1,t2)
                    if (v > t1[s]) { t1[s] = v; i1[s] = n; }
                }
            }
        }
    }

    // ---- cross-lane merge: overlay padded arrays on the tile LDS ----
    __syncthreads();
    float* mg1 = (float*)lds;              // [64][65]
    float* mg2 = (float*)(lds + 4160);     // [64][65]
    int*   mgi = lds + 8320;               // [64][65]
    if (tid == 0) nflag = 0;
    int col = wave * 16 + la;              // 0..63
    #pragma unroll
    for (int s = 0; s < 16; ++s) {
        int m = (s >> 2) * 16 + lq * 4 + (s & 3);
        mg1[m * 65 + col] = t1[s];
        mg2[m * 65 + col] = t2[s];
        mgi[m * 65 + col] = i1[s];
    }
    __syncthreads();

    if (tid < BM) {
        float best = -3.4e38f, sec = -3.4e38f, bw2 = -3.4e38f;
        int bi = 0x7fffffff;
        for (int c = 0; c < 64; ++c) {
            float v1 = mg1[tid * 65 + c];
            float v2 = mg2[tid * 65 + c];
            int  idx = mgi[tid * 65 + c];
            if (v1 > best || (v1 == best && idx < bi)) {
                sec = fmaxf(sec, best);
                best = v1; bi = idx; bw2 = v2;
            } else {
                sec = fmaxf(sec, v1);
            }
        }
        sec = fmaxf(sec, bw2);
        if (best - sec < TAU) {
            int p = atomicAdd(&nflag, 1);
            lst[p] = tid;                  // fp64 rescue
        } else {
            nxt[t * GN + gt * BM + tid] = (t + 1) * GN + bi;
        }
    }
    __syncthreads();

    // ---- fp64 rescue, wave-parallel (exact: matches rounds 1-2 fp64 path) ----
    int nf = nflag;
    const float* Bf = feat + (size_t)(t + 1) * GN * DK;
    for (int fi = wave; fi < nf; fi += 4) {
        int r = lst[fi];
        const float* Arow = feat + (size_t)(t * GN + gt * BM + r) * DK;
        double bv = -1e300; int bi2 = 0x7fffffff;
        for (int hh = 0; hh < 16; ++hh) {
            int h = hh * 64 + lane;
            const float* Brow = Bf + (size_t)h * DK;
            double s = 0.0;
            #pragma unroll 8
            for (int k = 0; k < DK; k += 4) {
                float4 a = *(const float4*)(Arow + k);
                float4 b = *(const float4*)(Brow + k);
                s = fma((double)a.x, (double)b.x, s);
                s = fma((double)a.y, (double)b.y, s);
                s = fma((double)a.z, (double)b.z, s);
                s = fma((double)a.w, (double)b.w, s);
            }
            s *= rnd[(t + 1) * GN + h];
            if (s > bv || (s == bv && h < bi2)) { bv = s; bi2 = h; }
        }
        #pragma unroll
        for (int off = 32; off > 0; off >>= 1) {
            double ov = __shfl_down(bv, off);
            int    oi = __shfl_down(bi2, off);
            if (ov > bv || (ov == bv && oi < bi2)) { bv = ov; bi2 = oi; }
        }
        if (lane == 0) nxt[t * GN + gt * BM + r] = (t + 1) * GN + bi2;
    }
}

// ---------------------------------------------------------------------------
// Kernel 3: chain propagation + lengths + kept-offset scan, one block.
// Packed winner word = (chain_priority << 7) | length; priorities are unique
// per target (one node per group per chain) so min picks the right length.
// Double-buffered winner array -> 2 syncs per timestep.
// ---------------------------------------------------------------------------
__global__ void kgraph(const int* __restrict__ nxt, int* __restrict__ chain_of,
                       int* __restrict__ clen, const int* __restrict__ minp,
                       int* __restrict__ offset) {
    __shared__ int winner[2 * GN];
    __shared__ int psum[1024];
    int g = threadIdx.x;            // 0..1023
    int mychain = g, mylen = 1;     // group 0: every node starts a chain
    chain_of[g] = g;
    winner[g] = 0x7fffffff;         // buffer 0 init
    int nxt_cur = nxt[g];           // prefetch t=0
    __syncthreads();
    for (int t = 0; t < TT - 1; ++t) {
        int* Wa = winner + (t & 1) * GN;
        int* Wb = winner + ((t + 1) & 1) * GN;
        int j = nxt_cur - (t + 1) * GN;         // target slot in next group
        if (t + 1 < TT - 1) nxt_cur = nxt[(t + 1) * GN + g];   // prefetch
        atomicMin(&Wa[j], (mychain << 7) | mylen);
        Wb[g] = 0x7fffffff;                     // prep next buffer
        __syncthreads();
        int w  = Wa[g];
        int wj = Wa[j];
        if ((wj >> 7) != mychain) clen[mychain] = mylen;   // chain dies here
        int node = (t + 1) * GN + g;
        if (w == 0x7fffffff) { mychain = node; mylen = 1; }
        else                 { mychain = w >> 7; mylen = (w & 127) + 1; }
        chain_of[node] = mychain;
        __syncthreads();            // Wa reads done before t+2 resets it
    }
    clen[mychain] = mylen;          // surviving chains end at group 63
    __syncthreads();

    // exclusive prefix sum of kept chain lengths over start indices
    int ml = *minp;
    int base = g * 64;
    int local = 0;
    for (int e = 0; e < 64; ++e) {
        int s = base + e;
        if (chain_of[s] == s) { int cl = clen[s]; if (cl >= ml) local += cl; }
    }
    psum[g] = local;
    __syncthreads();
    for (int off = 1; off < 1024; off <<= 1) {
        int add = (g >= off) ? psum[g - off] : 0;
        __syncthreads();
        psum[g] += add;
        __syncthreads();
    }
    int run = g ? psum[g - 1] : 0;
    for (int e = 0; e < 64; ++e) {
        int s = base + e;
        int v = 0;
        if (chain_of[s] == s) { int cl = clen[s]; if (cl >= ml) v = cl; }
        offset[s] = run;
        run += v;
    }
}

// ---------------------------------------------------------------------------
// Kernel 4: scatter kept rows, one wave per node (4 nodes / 256-thr block).
// ---------------------------------------------------------------------------
__global__ void kscatter(const float* __restrict__ coor, const float* __restrict__ feat,
                         const int* __restrict__ chain_of, const int* __restrict__ clen,
                         const int* __restrict__ offset, const int* __restrict__ minp,
                         float* __restrict__ out) {
    int node = blockIdx.x * 4 + (threadIdx.x >> 6);
    int lane = threadIdx.x & 63;
    int s = chain_of[node];
    if (clen[s] < *minp) return;
    int row = offset[s] + (node >> 10) - (s >> 10);
    float* orow = out + (size_t)row * OUTC;
    const float* f = feat + (size_t)node * DK;
    if (lane < 3) orow[lane] = coor[(size_t)node * 3 + lane];
    orow[3 + lane]  = f[lane];
    orow[67 + lane] = f[64 + lane];
}

// ---------------------------------------------------------------------------
extern "C" void kernel_launch(void* const* d_in, const int* in_sizes, int n_in,
                              void* d_out, int out_size, void* d_ws, size_t ws_size,
                              hipStream_t stream) {
    const float* coor   = (const float*)d_in[0];   // [N,3]
    const float* feat   = (const float*)d_in[1];   // [N,128]
    const int*   minlen = (const int*)d_in[2];     // scalar
    float*       out    = (float*)d_out;           // [N,131] fp32

    char* ws = (char*)d_ws;
    double*   rnd      = (double*)(ws);                            // N doubles
    float*    rnf      = (float*)(ws + (size_t)NN * 8);            // N floats
    int*      nxt      = (int*)(ws + (size_t)NN * 12);
    int*      chain_of = (int*)(ws + (size_t)NN * 16);
    int*      clen     = (int*)(ws + (size_t)NN * 20);
    int*      offset   = (int*)(ws + (size_t)NN * 24);
    unsigned* fh       = (unsigned*)(ws + (size_t)NN * 28);        // N*128 fp16 = 16 MB

    hipMemsetAsync(d_out, 0, (size_t)out_size * sizeof(float), stream);

    kconv<<<NN / 4, 256, 0, stream>>>(feat, fh, rnf, rnd);

    ksim<<<1024, 256, 0, stream>>>(feat, fh, rnf, rnd, nxt);

    kgraph<<<1, GN, 0, stream>>>(nxt, chain_of, clen, minlen, offset);
    kscatter<<<NN / 4, 256, 0, stream>>>(coor, feat, chain_of, clen, offset, minlen, out);
}